// Round 19
// baseline (95.117 us; speedup 1.0000x reference)
//
#include <hip/hip_runtime.h>

// SSIM loss, fused separable Gaussian (11x11, sigma=1.5) over [32,3,512,512] f32.
// R19 = R17 with the V-phase split across TWO wave-aligned row-groups
// (640-thread blocks, 10 waves):
//   group A = waves 0-4 (lane<266): stat rows 0-13  -> outputs 0-3
//   group B = waves 5-9 (lane<266): stat rows 4-17  -> outputs 4-7
//   Each group is an independent 14-row/4-output FIR (R11's V-shape):
//   V wall-time ~halves, serial load chain 18->14, accumulators 16->8
//   pairs/thread (fits the 32-VGPR regime the compiler enforces; R9/R18
//   liveness anchors proved source can't force more). Rows 4-13 are loaded
//   by both groups (+20 loads/col, L1-resident -- FETCH unchanged).
// H-phase unchanged from R17 (waves 0-7, one row-quad each).
// Kept: independent one-tile 8x256 blocks, XCD-bijective swizzle, pk f32x2
// chains, linear stats LDS, plain store + reduce kernel.

typedef float f32x2 __attribute__((ext_vector_type(2)));

#define IH 512
#define IW 512
#define TH 8                 // output rows per tile
#define TW 256               // output cols per tile
#define PW 266               // TW + 10 FIR cols
#define GRR 14               // raw rows per group (4 outputs + 10 halo)
#define LPW 268              // stats row stride in f32x2
#define HTILES 64
#define NBLK 12288           // 96 images * 64 ht * 2 wt
#define CPX 1536             // NBLK / 8 XCDs (exact -> bijective)
#define NPIX 25165824.0f     // 96*512*512
#define NTHR 640             // 10 waves: 2 V-groups x 5 waves

constexpr float GW[11] = {
    0.00102838f, 0.00759877f, 0.03600078f, 0.10936070f, 0.21300554f,
    0.26601173f,
    0.21300554f, 0.10936070f, 0.03600078f, 0.00759877f, 0.00102838f
};
constexpr float C1f = 0.0001f;  // 0.01^2
constexpr float C2f = 0.0009f;  // 0.03^2

__global__ __launch_bounds__(1024) void ssim_reduce(
    const float* __restrict__ ws, float* __restrict__ out)
{
    __shared__ float wsum[16];
    const int tid = threadIdx.x;
    const float4* w4 = reinterpret_cast<const float4*>(ws);  // 3072 float4
    float s = 0.0f;
    #pragma unroll
    for (int i = 0; i < 3; ++i) {
        const float4 v = w4[tid + i * 1024];
        s += (v.x + v.y) + (v.z + v.w);
    }
    #pragma unroll
    for (int off = 32; off > 0; off >>= 1) s += __shfl_down(s, off, 64);
    if ((tid & 63) == 0) wsum[tid >> 6] = s;
    __syncthreads();
    if (tid == 0) {
        float t = 0.f;
        #pragma unroll
        for (int i = 0; i < 16; ++i) t += wsum[i];
        out[0] = 1.0f - t * (1.0f / NPIX);
    }
}

__global__ __launch_bounds__(NTHR, 3) void ssim_main(
    const float* __restrict__ pred,
    const float* __restrict__ targ,
    float* __restrict__ ws)
{
    __shared__ __align__(16) f32x2 lds01[TH][LPW];   // (E[p], E[t])
    __shared__ __align__(16) f32x2 lds23[TH][LPW];   // (E[p^2+t^2], E[p*t])
    __shared__ float wsum[10];

    const int tid = threadIdx.x;

    // -------- XCD-bijective swizzle: tl-consecutive tiles share an XCD -----
    const int b  = blockIdx.x;
    const int tl = (b & 7) * CPX + (b >> 3);
    const int ht = tl & (HTILES - 1);            // consecutive ht share rows
    const int wt = (tl >> 6) & 1;
    const int bc = tl >> 7;

    const int rbase = ht * TH - 5;
    const bool vint = (ht != 0) && (ht != HTILES - 1);   // uniform
    const float* __restrict__ P = pred + (size_t)bc * (IH * IW);
    const float* __restrict__ T = targ + (size_t)bc * (IH * IW);

    // -------- V-group decomposition (wave-aligned: 320 = 5 waves) ----------
    const int grp  = tid / 320;                  // 0: rows 0-13 / outs 0-3
    const int lane = tid - grp * 320;            // 1: rows 4-17 / outs 4-7
    const int gbase = rbase + grp * 4;           // group's first stat row

    // ---------------- V-phase: 14-row column FIR per group -----------------
    if (lane < PW) {
        const int w = wt * TW - 5 + lane;
        const float wm = ((unsigned)w < (unsigned)IW) ? 1.0f : 0.0f;
        const int wc = w < 0 ? 0 : (w > IW - 1 ? IW - 1 : w);

        float pv[GRR], tv[GRR];
        if (vint) {
            // interior: no clamps, no masks
            const float* __restrict__ Pp = P + (size_t)gbase * IW + wc;
            const float* __restrict__ Tp = T + (size_t)gbase * IW + wc;
            #pragma unroll
            for (int rr = 0; rr < GRR; ++rr) pv[rr] = Pp[(size_t)rr * IW];
            #pragma unroll
            for (int rr = 0; rr < GRR; ++rr) tv[rr] = Tp[(size_t)rr * IW];
        } else {
            // border: clamp rows + zero masks
            #pragma unroll
            for (int rr = 0; rr < GRR; ++rr) {
                const int h = gbase + rr;
                const int hc = h < 0 ? 0 : (h > IH - 1 ? IH - 1 : h);
                const float rmk = ((unsigned)h < (unsigned)IH) ? 1.0f : 0.0f;
                pv[rr] = P[(size_t)hc * IW + wc] * rmk;
                tv[rr] = T[(size_t)hc * IW + wc] * rmk;
            }
        }
        __builtin_amdgcn_sched_barrier(0);   // keep loads ahead of FIR

        f32x2 a01[4], a23[4];
        #pragma unroll
        for (int q = 0; q < 4; ++q) {
            a01[q] = (f32x2){0.f, 0.f};
            a23[q] = (f32x2){0.f, 0.f};
        }

        #pragma unroll
        for (int rr = 0; rr < GRR; ++rr) {
            const float p = pv[rr], t = tv[rr];
            f32x2 s01; s01.x = p; s01.y = t;
            f32x2 s23;
            s23.x = fmaf(p, p, t * t);        // p^2 + t^2
            s23.y = p * t;                    // p*t
            #pragma unroll
            for (int q = 0; q < 4; ++q) {
                const int k = rr - q;         // static after unroll
                if (k >= 0 && k < 11) {
                    const f32x2 g = {GW[k], GW[k]};
                    a01[q] = __builtin_elementwise_fma(g, s01, a01[q]);
                    a23[q] = __builtin_elementwise_fma(g, s23, a23[q]);
                }
            }
        }
        const f32x2 wmv = {wm, wm};
        #pragma unroll
        for (int q = 0; q < 4; ++q) {
            const int ro = grp * 4 + q;
            lds01[ro][lane] = a01[q] * wmv;
            lds23[ro][lane] = a23[q] * wmv;
        }
    }
    __syncthreads();

    // ---------------- H-phase: waves 0-7, one row-quad each ----------------
    float lsum = 0.0f;
    if (tid < 512) {
        const int r  = tid >> 6;            // 0..7 (one row per wave)
        const int c0 = (tid & 63) << 2;     // 0..252 (f32x2 elements)

        float4 u4[7], v4[7];
        const float4* b01 = reinterpret_cast<const float4*>(&lds01[r][c0]);
        const float4* b23 = reinterpret_cast<const float4*>(&lds23[r][c0]);
        #pragma unroll
        for (int q = 0; q < 7; ++q) { u4[q] = b01[q]; v4[q] = b23[q]; }
        const f32x2* x01 = reinterpret_cast<const f32x2*>(u4);   // 14 elems
        const f32x2* x23 = reinterpret_cast<const f32x2*>(v4);

        #pragma unroll
        for (int j = 0; j < 4; ++j) {
            f32x2 acc01 = {0.f, 0.f};
            f32x2 acc23 = {0.f, 0.f};
            #pragma unroll
            for (int k = 0; k < 11; ++k) {
                const f32x2 g = {GW[k], GW[k]};
                acc01 = __builtin_elementwise_fma(g, x01[j + k], acc01);
                acc23 = __builtin_elementwise_fma(g, x23[j + k], acc23);
            }
            const float m1  = acc01.x;
            const float m2  = acc01.y;
            const float sPP = acc23.x;      // E[p^2]+E[t^2]
            const float e12 = acc23.y;      // E[p*t]
            const float m1m2 = m1 * m2;
            const float msq  = fmaf(m1, m1, m2 * m2);
            const float num = fmaf(2.0f, m1m2, C1f) * fmaf(2.0f, (e12 - m1m2), C2f);
            const float den = (msq + C1f) * ((sPP - msq) + C2f);
            lsum = fmaf(num, __builtin_amdgcn_rcpf(den), lsum);
        }
    }

    // ---------------- Reduction: wave shuffle -> LDS -> plain store --------
    #pragma unroll
    for (int off = 32; off > 0; off >>= 1) lsum += __shfl_down(lsum, off, 64);
    const int wl = tid & 63;
    const int wv = tid >> 6;                // 0..9
    if (wl == 0) wsum[wv] = lsum;
    __syncthreads();
    if (tid == 0) {
        float bs = 0.f;
        #pragma unroll
        for (int i = 0; i < 10; ++i) bs += wsum[i];
        ws[b] = bs;
    }
}

extern "C" void kernel_launch(void* const* d_in, const int* in_sizes, int n_in,
                              void* d_out, int out_size, void* d_ws, size_t ws_size,
                              hipStream_t stream) {
    const float* pred = (const float*)d_in[0];
    const float* targ = (const float*)d_in[1];
    float* out = (float*)d_out;
    float* wsf = (float*)d_ws;               // needs 12288 floats = 48 KB

    hipLaunchKernelGGL(ssim_main, dim3(NBLK), dim3(NTHR), 0, stream,
                       pred, targ, wsf);
    hipLaunchKernelGGL(ssim_reduce, dim3(1), dim3(1024), 0, stream, wsf, out);
}

// Round 20
// 79.265 us; speedup vs baseline: 1.2000x; 1.2000x over previous
//
#include <hip/hip_runtime.h>

// SSIM loss, fused separable Gaussian (11x11, sigma=1.5) over [32,3,512,512] f32.
// R20: full-width tile 4x512, 512-thread blocks (8 waves), BOTH phases
// fully wave-wide:
//  - V-phase: 512 threads = 512 interior stat columns (PW=522; the 10 halo
//    cols are identically ZERO because the reference zero-pads -> 10 threads
//    just write zero pads). NO column masks, NO clamps in the hot path.
//    (R17 ran V on 266/512 lanes -> half the issue width idled ~45% of the
//    block lifetime; that imbalance is this round's target.)
//  - TH=4 keeps LDS at 33.5 KB -> 4 blocks/CU x 8 waves = 32 waves = 100% cap.
//  - H-phase: 512 threads, r=tid>>7 (wave-uniform), 4 outputs each, 32B lane
//    stride reads (known-good ~4-way, NOT R15's 64B/16-way).
//  - cost accepted: vertical load amp 2.25->3.5x (L2-absorbed).
//  - border rows: uniform branch, only ht<2 || ht>125 (clamp+mask there).
// Kept: independent one-tile blocks, XCD-bijective swizzle, pk f32x2 chains,
// plain store ws[b] + reduce kernel.

typedef float f32x2 __attribute__((ext_vector_type(2)));

#define IH 512
#define IW 512
#define TH 4                 // output rows per tile
#define TW 512               // output cols per tile (full width)
#define RRN 14               // raw rows per tile
#define LPW 524              // stats row stride in f32x2 (col c at idx c+5)
#define HTILES 128
#define NBLK 12288           // 96 images * 128 ht
#define CPX 1536             // NBLK / 8 XCDs (exact -> bijective)
#define NPIX 25165824.0f     // 96*512*512
#define NTHR 512

constexpr float GW[11] = {
    0.00102838f, 0.00759877f, 0.03600078f, 0.10936070f, 0.21300554f,
    0.26601173f,
    0.21300554f, 0.10936070f, 0.03600078f, 0.00759877f, 0.00102838f
};
constexpr float C1f = 0.0001f;  // 0.01^2
constexpr float C2f = 0.0009f;  // 0.03^2

__global__ __launch_bounds__(1024) void ssim_reduce(
    const float* __restrict__ ws, float* __restrict__ out)
{
    __shared__ float wsum[16];
    const int tid = threadIdx.x;
    const float4* w4 = reinterpret_cast<const float4*>(ws);  // 3072 float4
    float s = 0.0f;
    #pragma unroll
    for (int i = 0; i < 3; ++i) {
        const float4 v = w4[tid + i * 1024];
        s += (v.x + v.y) + (v.z + v.w);
    }
    #pragma unroll
    for (int off = 32; off > 0; off >>= 1) s += __shfl_down(s, off, 64);
    if ((tid & 63) == 0) wsum[tid >> 6] = s;
    __syncthreads();
    if (tid == 0) {
        float t = 0.f;
        #pragma unroll
        for (int i = 0; i < 16; ++i) t += wsum[i];
        out[0] = 1.0f - t * (1.0f / NPIX);
    }
}

__global__ __launch_bounds__(NTHR, 8) void ssim_main(
    const float* __restrict__ pred,
    const float* __restrict__ targ,
    float* __restrict__ ws)
{
    __shared__ __align__(16) f32x2 lds01[TH][LPW];   // (E[p], E[t])
    __shared__ __align__(16) f32x2 lds23[TH][LPW];   // (E[p^2+t^2], E[p*t])
    __shared__ float wsum[8];

    const int tid = threadIdx.x;

    // -------- XCD-bijective swizzle: ht-consecutive tiles share an XCD -----
    const int b  = blockIdx.x;
    const int tl = (b & 7) * CPX + (b >> 3);
    const int ht = tl & (HTILES - 1);            // consecutive ht share rows
    const int bc = tl >> 7;

    const int rbase = ht * TH - 5;
    const bool vint = (rbase >= 0) && (rbase + RRN <= IH);   // ht in [2,125]
    const float* __restrict__ P = pred + (size_t)bc * (IH * IW);
    const float* __restrict__ T = targ + (size_t)bc * (IH * IW);

    // ---------------- V-phase: all 512 threads, one interior column --------
    {
        const int wc = tid;                      // column 0..511, always valid

        float pv[RRN], tv[RRN];
        if (vint) {
            // interior: no clamps, no masks
            const float* __restrict__ Pp = P + (size_t)rbase * IW + wc;
            const float* __restrict__ Tp = T + (size_t)rbase * IW + wc;
            #pragma unroll
            for (int rr = 0; rr < RRN; ++rr) pv[rr] = Pp[(size_t)rr * IW];
            #pragma unroll
            for (int rr = 0; rr < RRN; ++rr) tv[rr] = Tp[(size_t)rr * IW];
        } else {
            // border rows: clamp + zero mask (uniform branch, ht<2 or >125)
            #pragma unroll
            for (int rr = 0; rr < RRN; ++rr) {
                const int h = rbase + rr;
                const int hc = h < 0 ? 0 : (h > IH - 1 ? IH - 1 : h);
                const float rmk = ((unsigned)h < (unsigned)IH) ? 1.0f : 0.0f;
                pv[rr] = P[(size_t)hc * IW + wc] * rmk;
                tv[rr] = T[(size_t)hc * IW + wc] * rmk;
            }
        }
        __builtin_amdgcn_sched_barrier(0);   // keep loads ahead of FIR

        f32x2 a01[TH], a23[TH];
        #pragma unroll
        for (int q = 0; q < TH; ++q) {
            a01[q] = (f32x2){0.f, 0.f};
            a23[q] = (f32x2){0.f, 0.f};
        }

        #pragma unroll
        for (int rr = 0; rr < RRN; ++rr) {
            const float p = pv[rr], t = tv[rr];
            f32x2 s01; s01.x = p; s01.y = t;
            f32x2 s23;
            s23.x = fmaf(p, p, t * t);        // p^2 + t^2
            s23.y = p * t;                    // p*t
            #pragma unroll
            for (int q = 0; q < TH; ++q) {
                const int k = rr - q;         // static after unroll
                if (k >= 0 && k < 11) {
                    const f32x2 g = {GW[k], GW[k]};
                    a01[q] = __builtin_elementwise_fma(g, s01, a01[q]);
                    a23[q] = __builtin_elementwise_fma(g, s23, a23[q]);
                }
            }
        }
        #pragma unroll
        for (int q = 0; q < TH; ++q) {
            lds01[q][tid + 5] = a01[q];       // col c at idx c+5; no masks
            lds23[q][tid + 5] = a23[q];
        }
        // zero pads: idx 0-4 (cols -5..-1) and 517-521 (cols 512..516)
        if (tid < 10) {
            const int pi = (tid < 5) ? tid : (512 + tid);   // 0-4 / 517-521
            const f32x2 z = {0.f, 0.f};
            #pragma unroll
            for (int q = 0; q < TH; ++q) {
                lds01[q][pi] = z;
                lds23[q][pi] = z;
            }
        }
    }
    __syncthreads();

    // ---------------- H-phase: all 512 threads, one row-quad each ----------
    float lsum = 0.0f;
    {
        const int r  = tid >> 7;            // 0..3 (wave-uniform)
        const int c0 = (tid & 127) << 2;    // elem base, 0..508

        // output col c = c0+j taps stat idx c+k (k=0..10) -> elems c0..c0+13
        float4 u4[7], v4[7];
        const float4* b01 = reinterpret_cast<const float4*>(&lds01[r][c0]);
        const float4* b23 = reinterpret_cast<const float4*>(&lds23[r][c0]);
        #pragma unroll
        for (int q = 0; q < 7; ++q) { u4[q] = b01[q]; v4[q] = b23[q]; }
        const f32x2* x01 = reinterpret_cast<const f32x2*>(u4);   // 14 elems
        const f32x2* x23 = reinterpret_cast<const f32x2*>(v4);

        #pragma unroll
        for (int j = 0; j < 4; ++j) {
            f32x2 acc01 = {0.f, 0.f};
            f32x2 acc23 = {0.f, 0.f};
            #pragma unroll
            for (int k = 0; k < 11; ++k) {
                const f32x2 g = {GW[k], GW[k]};
                acc01 = __builtin_elementwise_fma(g, x01[j + k], acc01);
                acc23 = __builtin_elementwise_fma(g, x23[j + k], acc23);
            }
            const float m1  = acc01.x;
            const float m2  = acc01.y;
            const float sPP = acc23.x;      // E[p^2]+E[t^2]
            const float e12 = acc23.y;      // E[p*t]
            const float m1m2 = m1 * m2;
            const float msq  = fmaf(m1, m1, m2 * m2);
            const float num = fmaf(2.0f, m1m2, C1f) * fmaf(2.0f, (e12 - m1m2), C2f);
            const float den = (msq + C1f) * ((sPP - msq) + C2f);
            lsum = fmaf(num, __builtin_amdgcn_rcpf(den), lsum);
        }
    }

    // ---------------- Reduction: wave shuffle -> LDS -> plain store --------
    #pragma unroll
    for (int off = 32; off > 0; off >>= 1) lsum += __shfl_down(lsum, off, 64);
    const int lane = tid & 63;
    const int wv   = tid >> 6;              // 0..7
    if (lane == 0) wsum[wv] = lsum;
    __syncthreads();
    if (tid == 0) {
        float bs = 0.f;
        #pragma unroll
        for (int i = 0; i < 8; ++i) bs += wsum[i];
        ws[b] = bs;
    }
}

extern "C" void kernel_launch(void* const* d_in, const int* in_sizes, int n_in,
                              void* d_out, int out_size, void* d_ws, size_t ws_size,
                              hipStream_t stream) {
    const float* pred = (const float*)d_in[0];
    const float* targ = (const float*)d_in[1];
    float* out = (float*)d_out;
    float* wsf = (float*)d_ws;               // needs 12288 floats = 48 KB

    hipLaunchKernelGGL(ssim_main, dim3(NBLK), dim3(NTHR), 0, stream,
                       pred, targ, wsf);
    hipLaunchKernelGGL(ssim_reduce, dim3(1), dim3(1024), 0, stream, wsf, out);
}

// Round 21
// 78.630 us; speedup vs baseline: 1.2097x; 1.0081x over previous
//
#include <hip/hip_runtime.h>

// SSIM loss, fused separable Gaussian (11x11, sigma=1.5) over [32,3,512,512] f32.
// R21 = R20 + scalar-row-base V addressing (single-variable change):
//   R20's interior loads Pp[rr*IW] use a per-thread 64b base -> the 2KB row
//   stride exceeds the 13-bit imm offset, so the backend materializes VALU
//   64b address adds every ~2 rows (~30-60 VALU/col). Computing the row
//   pointer UNIFORMLY per row (P + (rbase+rr)*IW, SALU) with one per-lane
//   voffset (wc*4) lets it emit global_load v, v_off, s[rowbase]: address
//   stepping on the scalar unit, ~8-12% fewer VALU instructions.
// Kept from R20: 4x512 full-width tile, 512-thread blocks, both phases
// wave-wide, no column masks (10 zero pads), uniform border branch ht<2/>125,
// XCD-bijective swizzle, pk f32x2 chains, linear stats LDS (32B-stride H
// reads), plain store ws[b] + reduce kernel.

typedef float f32x2 __attribute__((ext_vector_type(2)));

#define IH 512
#define IW 512
#define TH 4                 // output rows per tile
#define RRN 14               // raw rows per tile
#define LPW 524              // stats row stride in f32x2 (col c at idx c+5)
#define HTILES 128
#define NBLK 12288           // 96 images * 128 ht
#define CPX 1536             // NBLK / 8 XCDs (exact -> bijective)
#define NPIX 25165824.0f     // 96*512*512
#define NTHR 512

constexpr float GW[11] = {
    0.00102838f, 0.00759877f, 0.03600078f, 0.10936070f, 0.21300554f,
    0.26601173f,
    0.21300554f, 0.10936070f, 0.03600078f, 0.00759877f, 0.00102838f
};
constexpr float C1f = 0.0001f;  // 0.01^2
constexpr float C2f = 0.0009f;  // 0.03^2

__global__ __launch_bounds__(1024) void ssim_reduce(
    const float* __restrict__ ws, float* __restrict__ out)
{
    __shared__ float wsum[16];
    const int tid = threadIdx.x;
    const float4* w4 = reinterpret_cast<const float4*>(ws);  // 3072 float4
    float s = 0.0f;
    #pragma unroll
    for (int i = 0; i < 3; ++i) {
        const float4 v = w4[tid + i * 1024];
        s += (v.x + v.y) + (v.z + v.w);
    }
    #pragma unroll
    for (int off = 32; off > 0; off >>= 1) s += __shfl_down(s, off, 64);
    if ((tid & 63) == 0) wsum[tid >> 6] = s;
    __syncthreads();
    if (tid == 0) {
        float t = 0.f;
        #pragma unroll
        for (int i = 0; i < 16; ++i) t += wsum[i];
        out[0] = 1.0f - t * (1.0f / NPIX);
    }
}

__global__ __launch_bounds__(NTHR, 8) void ssim_main(
    const float* __restrict__ pred,
    const float* __restrict__ targ,
    float* __restrict__ ws)
{
    __shared__ __align__(16) f32x2 lds01[TH][LPW];   // (E[p], E[t])
    __shared__ __align__(16) f32x2 lds23[TH][LPW];   // (E[p^2+t^2], E[p*t])
    __shared__ float wsum[8];

    const int tid = threadIdx.x;

    // -------- XCD-bijective swizzle: ht-consecutive tiles share an XCD -----
    const int b  = blockIdx.x;
    const int tl = (b & 7) * CPX + (b >> 3);
    const int ht = tl & (HTILES - 1);            // consecutive ht share rows
    const int bc = tl >> 7;

    const int rbase = ht * TH - 5;
    const bool vint = (rbase >= 0) && (rbase + RRN <= IH);   // ht in [2,125]
    const float* __restrict__ P = pred + (size_t)bc * (IH * IW);
    const float* __restrict__ T = targ + (size_t)bc * (IH * IW);

    // ---------------- V-phase: all 512 threads, one interior column --------
    {
        const int wc = tid;                      // column 0..511, always valid

        float pv[RRN], tv[RRN];
        if (vint) {
            // interior: uniform (SALU) row base per row + per-lane voffset
            #pragma unroll
            for (int rr = 0; rr < RRN; ++rr) {
                const float* __restrict__ rowP = P + (size_t)(rbase + rr) * IW;
                const float* __restrict__ rowT = T + (size_t)(rbase + rr) * IW;
                pv[rr] = rowP[wc];
                tv[rr] = rowT[wc];
            }
        } else {
            // border rows: clamp + zero mask (uniform branch, ht<2 or >125)
            #pragma unroll
            for (int rr = 0; rr < RRN; ++rr) {
                const int h = rbase + rr;
                const int hc = h < 0 ? 0 : (h > IH - 1 ? IH - 1 : h);
                const float rmk = ((unsigned)h < (unsigned)IH) ? 1.0f : 0.0f;
                const float* __restrict__ rowP = P + (size_t)hc * IW;
                const float* __restrict__ rowT = T + (size_t)hc * IW;
                pv[rr] = rowP[wc] * rmk;
                tv[rr] = rowT[wc] * rmk;
            }
        }

        f32x2 a01[TH], a23[TH];
        #pragma unroll
        for (int q = 0; q < TH; ++q) {
            a01[q] = (f32x2){0.f, 0.f};
            a23[q] = (f32x2){0.f, 0.f};
        }

        #pragma unroll
        for (int rr = 0; rr < RRN; ++rr) {
            const float p = pv[rr], t = tv[rr];
            f32x2 s01; s01.x = p; s01.y = t;
            f32x2 s23;
            s23.x = fmaf(p, p, t * t);        // p^2 + t^2
            s23.y = p * t;                    // p*t
            #pragma unroll
            for (int q = 0; q < TH; ++q) {
                const int k = rr - q;         // static after unroll
                if (k >= 0 && k < 11) {
                    const f32x2 g = {GW[k], GW[k]};
                    a01[q] = __builtin_elementwise_fma(g, s01, a01[q]);
                    a23[q] = __builtin_elementwise_fma(g, s23, a23[q]);
                }
            }
        }
        #pragma unroll
        for (int q = 0; q < TH; ++q) {
            lds01[q][tid + 5] = a01[q];       // col c at idx c+5; no masks
            lds23[q][tid + 5] = a23[q];
        }
        // zero pads: idx 0-4 (cols -5..-1) and 517-521 (cols 512..516)
        if (tid < 10) {
            const int pi = (tid < 5) ? tid : (512 + tid);   // 0-4 / 517-521
            const f32x2 z = {0.f, 0.f};
            #pragma unroll
            for (int q = 0; q < TH; ++q) {
                lds01[q][pi] = z;
                lds23[q][pi] = z;
            }
        }
    }
    __syncthreads();

    // ---------------- H-phase: all 512 threads, one row-quad each ----------
    float lsum = 0.0f;
    {
        const int r  = tid >> 7;            // 0..3 (wave-uniform)
        const int c0 = (tid & 127) << 2;    // elem base, 0..508

        // output col c = c0+j taps stat idx c+k (k=0..10) -> elems c0..c0+13
        float4 u4[7], v4[7];
        const float4* b01 = reinterpret_cast<const float4*>(&lds01[r][c0]);
        const float4* b23 = reinterpret_cast<const float4*>(&lds23[r][c0]);
        #pragma unroll
        for (int q = 0; q < 7; ++q) { u4[q] = b01[q]; v4[q] = b23[q]; }
        const f32x2* x01 = reinterpret_cast<const f32x2*>(u4);   // 14 elems
        const f32x2* x23 = reinterpret_cast<const f32x2*>(v4);

        #pragma unroll
        for (int j = 0; j < 4; ++j) {
            f32x2 acc01 = {0.f, 0.f};
            f32x2 acc23 = {0.f, 0.f};
            #pragma unroll
            for (int k = 0; k < 11; ++k) {
                const f32x2 g = {GW[k], GW[k]};
                acc01 = __builtin_elementwise_fma(g, x01[j + k], acc01);
                acc23 = __builtin_elementwise_fma(g, x23[j + k], acc23);
            }
            const float m1  = acc01.x;
            const float m2  = acc01.y;
            const float sPP = acc23.x;      // E[p^2]+E[t^2]
            const float e12 = acc23.y;      // E[p*t]
            const float m1m2 = m1 * m2;
            const float msq  = fmaf(m1, m1, m2 * m2);
            const float num = fmaf(2.0f, m1m2, C1f) * fmaf(2.0f, (e12 - m1m2), C2f);
            const float den = (msq + C1f) * ((sPP - msq) + C2f);
            lsum = fmaf(num, __builtin_amdgcn_rcpf(den), lsum);
        }
    }

    // ---------------- Reduction: wave shuffle -> LDS -> plain store --------
    #pragma unroll
    for (int off = 32; off > 0; off >>= 1) lsum += __shfl_down(lsum, off, 64);
    const int lane = tid & 63;
    const int wv   = tid >> 6;              // 0..7
    if (lane == 0) wsum[wv] = lsum;
    __syncthreads();
    if (tid == 0) {
        float bs = 0.f;
        #pragma unroll
        for (int i = 0; i < 8; ++i) bs += wsum[i];
        ws[b] = bs;
    }
}

extern "C" void kernel_launch(void* const* d_in, const int* in_sizes, int n_in,
                              void* d_out, int out_size, void* d_ws, size_t ws_size,
                              hipStream_t stream) {
    const float* pred = (const float*)d_in[0];
    const float* targ = (const float*)d_in[1];
    float* out = (float*)d_out;
    float* wsf = (float*)d_ws;               // needs 12288 floats = 48 KB

    hipLaunchKernelGGL(ssim_main, dim3(NBLK), dim3(NTHR), 0, stream,
                       pred, targ, wsf);
    hipLaunchKernelGGL(ssim_reduce, dim3(1), dim3(1024), 0, stream, wsf, out);
}